// Round 4
// baseline (394.724 us; speedup 1.0000x reference)
//
#include <hip/hip_runtime.h>
#include <hip/hip_bf16.h>
#include <float.h>

#define IN_F 256
#define HD   128   // H*D
#define NH   4

typedef __bf16 bf16x8 __attribute__((ext_vector_type(8)));
typedef __bf16 bf16x2 __attribute__((ext_vector_type(2)));
typedef float  f32x4  __attribute__((ext_vector_type(4)));

__device__ __forceinline__ bf16x8 cvt8(const float4 a, const float4 b) {
    bf16x8 r;
    r[0] = (__bf16)a.x; r[1] = (__bf16)a.y; r[2] = (__bf16)a.z; r[3] = (__bf16)a.w;
    r[4] = (__bf16)b.x; r[5] = (__bf16)b.y; r[6] = (__bf16)b.z; r[7] = (__bf16)b.w;
    return r;
}

// ---------------------------------------------------------------------------
// Pre-swizzle W into MFMA B-fragment order, bf16:
// wfrag[((ks*8+ct)*64 + lane)*8 + j] = w[(ct*16+(lane&15))*256 + ks*32+(lane>>4)*8+j]
// 4096 threads, one fragment (8 elems) each.
// ---------------------------------------------------------------------------
__global__ __launch_bounds__(256) void wprep_k(const float* __restrict__ w,
                                               __bf16* __restrict__ wfrag) {
    const int idx = blockIdx.x * 256 + threadIdx.x;   // 0..4095
    const int lane = idx & 63;
    const int ct = (idx >> 6) & 7;
    const int ks = idx >> 9;
    const float* p = w + (size_t)(ct * 16 + (lane & 15)) * IN_F + ks * 32 + (lane >> 4) * 8;
    const float4 v0 = *(const float4*)p;
    const float4 v1 = *(const float4*)(p + 4);
    *(bf16x8*)&wfrag[(size_t)idx * 8] = cvt8(v0, v1);
}

// ---------------------------------------------------------------------------
// LDS-free, barrier-free MFMA GEMM + fused el/er epilogue.
// Block 256 = 4 waves; wave w covers rows blockIdx*128 + w*32 .. +31
// (two 16-row m-tiles). A-frags loaded straight from feat (fp32->bf16),
// B-frags from L2-resident wfrag. C/D: col=ct*16+(lane&15),
// row = (lane>>4)*4+reg (HW-verified rounds 2-3).
// Epilogue also computes el/er: dot over features = 2 FMA per head per
// (mt,reg) from the ct-pair, then 4-step shfl_xor reduce over the 16 lanes
// of each quad; lanes il<4 write el heads, il 4..7 write er heads.
// ---------------------------------------------------------------------------
__global__ __launch_bounds__(256) void gemm_ft_fused(const float* __restrict__ feat,
                                                     const __bf16* __restrict__ wfrag,
                                                     const float* __restrict__ attn_l,
                                                     const float* __restrict__ attn_r,
                                                     __bf16* __restrict__ ft,
                                                     float* __restrict__ el,
                                                     float* __restrict__ er, int N) {
    const int t = threadIdx.x;
    const int wv = t >> 6;
    const int lane = t & 63;
    const int il = lane & 15;
    const int fk = (lane >> 4) * 8;
    const int rbase = blockIdx.x * 128 + wv * 32;   // wave's 32-row window

    f32x4 acc[2][8];
#pragma unroll
    for (int mt = 0; mt < 2; ++mt)
#pragma unroll
        for (int ct = 0; ct < 8; ++ct) acc[mt][ct] = {0.f, 0.f, 0.f, 0.f};

    const int r0 = rbase + il;          // A-frag row, m-tile 0
    const int r1 = rbase + 16 + il;     // A-frag row, m-tile 1

    for (int ks = 0; ks < 8; ++ks) {
        bf16x8 af0, af1;
        {
            if (r0 < N) {
                const float* p = feat + (size_t)r0 * IN_F + ks * 32 + fk;
                af0 = cvt8(*(const float4*)p, *(const float4*)(p + 4));
            } else {
#pragma unroll
                for (int i = 0; i < 8; ++i) af0[i] = (__bf16)0.f;
            }
            if (r1 < N) {
                const float* p = feat + (size_t)r1 * IN_F + ks * 32 + fk;
                af1 = cvt8(*(const float4*)p, *(const float4*)(p + 4));
            } else {
#pragma unroll
                for (int i = 0; i < 8; ++i) af1[i] = (__bf16)0.f;
            }
        }
        const bf16x8* bp = (const bf16x8*)&wfrag[(size_t)(ks * 8) * 512 + lane * 8];
#pragma unroll
        for (int ct = 0; ct < 8; ++ct) {
            const bf16x8 bfrag = bp[ct * 64];
            acc[0][ct] = __builtin_amdgcn_mfma_f32_16x16x32_bf16(af0, bfrag, acc[0][ct], 0, 0, 0);
            acc[1][ct] = __builtin_amdgcn_mfma_f32_16x16x32_bf16(af1, bfrag, acc[1][ct], 0, 0, 0);
        }
    }

    // per-lane attn vectors: AL[ct] = attn_l[ct*16+il]
    float AL[8], AR[8];
#pragma unroll
    for (int ct = 0; ct < 8; ++ct) {
        AL[ct] = attn_l[ct * 16 + il];
        AR[ct] = attn_r[ct * 16 + il];
    }

    const int rquad = (lane >> 4) * 4;  // quad's row offset within 16-row tile
#pragma unroll
    for (int mt = 0; mt < 2; ++mt) {
#pragma unroll
        for (int reg = 0; reg < 4; ++reg) {
            const int row = rbase + mt * 16 + rquad + reg;
            // ft store (bf16)
#pragma unroll
            for (int ct = 0; ct < 8; ++ct)
                if (row < N) ft[(size_t)row * HD + ct * 16 + il] = (__bf16)acc[mt][ct][reg];
            // el/er: per-head dot
            float pl[NH], pr[NH];
#pragma unroll
            for (int h = 0; h < NH; ++h) {
                const float v0 = acc[mt][2 * h][reg], v1 = acc[mt][2 * h + 1][reg];
                pl[h] = v0 * AL[2 * h] + v1 * AL[2 * h + 1];
                pr[h] = v0 * AR[2 * h] + v1 * AR[2 * h + 1];
            }
#pragma unroll
            for (int s = 1; s < 16; s <<= 1) {
#pragma unroll
                for (int h = 0; h < NH; ++h) {
                    pl[h] += __shfl_xor(pl[h], s);
                    pr[h] += __shfl_xor(pr[h], s);
                }
            }
            if (il < 8 && row < N) {
                const int h = il & 3;
                const float v = (h == 0) ? ((il < 4) ? pl[0] : pr[0])
                              : (h == 1) ? ((il < 4) ? pl[1] : pr[1])
                              : (h == 2) ? ((il < 4) ? pl[2] : pr[2])
                                         : ((il < 4) ? pl[3] : pr[3]);
                ((il < 4) ? el : er)[(size_t)row * NH + h] = v;
            }
        }
    }
}

// ---------------------------------------------------------------------------
// CSR build
// ---------------------------------------------------------------------------
__global__ __launch_bounds__(256) void deg_rank_k(const int* __restrict__ dst,
                                                  int* __restrict__ deg,
                                                  int* __restrict__ rank, int E) {
    const int i = blockIdx.x * 256 + threadIdx.x;
    if (i < E) rank[i] = atomicAdd(&deg[dst[i]], 1);
}

// shuffle-based inclusive scan, 1024 thr/block (16 waves), 2 barriers
__global__ __launch_bounds__(1024) void scan1_k(const int* __restrict__ deg,
                                                int* __restrict__ off,
                                                int* __restrict__ bsum, int N) {
    __shared__ int wsum[16];
    const int t = threadIdx.x;
    const int lane = t & 63;
    const int wid = t >> 6;
    const int g = blockIdx.x * 1024 + t;
    const int x = (g < N) ? deg[g] : 0;
    int v = x;
#pragma unroll
    for (int s = 1; s < 64; s <<= 1) {
        const int u = __shfl_up(v, s);
        if (lane >= s) v += u;
    }
    if (lane == 63) wsum[wid] = v;
    __syncthreads();
    if (t < 16) {
        int wv_ = wsum[t];
#pragma unroll
        for (int s = 1; s < 16; s <<= 1) {
            const int u = __shfl_up(wv_, s);
            if (t >= s) wv_ += u;
        }
        wsum[t] = wv_;
    }
    __syncthreads();
    const int woff = wid ? wsum[wid - 1] : 0;
    if (g < N) off[g] = woff + v - x;
    if (t == 1023) bsum[blockIdx.x] = wsum[15];
}

__global__ __launch_bounds__(128) void scan2_k(const int* __restrict__ bsum,
                                               int* __restrict__ boff, int nb) {
    __shared__ int lds[128];
    const int t = threadIdx.x;
    const int x = (t < nb) ? bsum[t] : 0;
    lds[t] = x;
    __syncthreads();
    int v = x;
    for (int s = 1; s < 128; s <<= 1) {
        const int add = (t >= s) ? lds[t - s] : 0;
        __syncthreads();
        v += add;
        lds[t] = v;
        __syncthreads();
    }
    boff[t] = v - x;
}

__global__ __launch_bounds__(256) void scatter_k(const int* __restrict__ src,
                                                 const int* __restrict__ dst,
                                                 const int* __restrict__ off,
                                                 const int* __restrict__ boff,
                                                 const int* __restrict__ rank,
                                                 int* __restrict__ ssrc, int E) {
    const int i = blockIdx.x * 256 + threadIdx.x;
    if (i < E) {
        const int d = dst[i];
        const int p = off[d] + boff[d >> 10] + rank[i];
        ssrc[p] = src[i];
    }
}

// ---------------------------------------------------------------------------
// Aggregation: one wave per dst node. Exp phase fills 64 LDS slots (zeros
// beyond degree, sv=0 -> padded sweeps hit ft row 0 in L1: free). Sweep:
// 16 lanes/edge, 4 edges per slot-group, 16 edges (4 independent 16B-load
// chains) per iteration.
// ---------------------------------------------------------------------------
__global__ __launch_bounds__(64) void aggregate_k(const __bf16* __restrict__ ft,
                                                  const float* __restrict__ el,
                                                  const float* __restrict__ er,
                                                  const int* __restrict__ deg,
                                                  const int* __restrict__ off,
                                                  const int* __restrict__ boff,
                                                  const int* __restrict__ ssrc,
                                                  float* __restrict__ out, int N) {
    const int n = blockIdx.x;
    const int lane = threadIdx.x;
    const int il = lane & 15;       // feature group: f = il*8 .. il*8+7
    const int q  = lane >> 4;       // edge slot within group of 4
    const int h  = il >> 2;         // head of this feature group
    float4* outp = (float4*)(out + (size_t)n * HD);
    const int dn = deg[n];
    if (dn == 0) {
        if (q < 2) outp[il * 2 + q] = make_float4(0.f, 0.f, 0.f, 0.f);
        return;
    }
    const int start = off[n] + boff[n >> 10];
    const float4 er4 = *(const float4*)(er + (size_t)n * NH);

    __shared__ float a_lds[64 * NH];
    __shared__ int   s_lds[64];
    float4 ssum = make_float4(0.f, 0.f, 0.f, 0.f);
    float acc[8];
#pragma unroll
    for (int i = 0; i < 8; ++i) acc[i] = 0.f;

    for (int c0 = 0; c0 < dn; c0 += 64) {
        const int j = c0 + lane;
        float4 a = make_float4(0.f, 0.f, 0.f, 0.f);
        int sv = 0;
        if (j < dn) {
            sv = ssrc[start + j];
            float4 e = *(const float4*)(el + (size_t)sv * NH);
            e.x += er4.x; e.y += er4.y; e.z += er4.z; e.w += er4.w;
            e.x = e.x >= 0.f ? e.x : 0.2f * e.x;
            e.y = e.y >= 0.f ? e.y : 0.2f * e.y;
            e.z = e.z >= 0.f ? e.z : 0.2f * e.z;
            e.w = e.w >= 0.f ? e.w : 0.2f * e.w;
            a.x = __expf(e.x); a.y = __expf(e.y);
            a.z = __expf(e.z); a.w = __expf(e.w);
            ssum.x += a.x; ssum.y += a.y; ssum.z += a.z; ssum.w += a.w;
        }
        s_lds[lane] = sv;
        *(float4*)(a_lds + lane * NH) = a;
        __syncthreads();
        const int cnt16 = (min(64, dn - c0) + 15) & ~15;
        for (int j2 = 0; j2 < cnt16; j2 += 16) {   // 16 edges/iter, 4 load chains
            const int e0 = j2 + q, e1 = j2 + 4 + q, e2 = j2 + 8 + q, e3 = j2 + 12 + q;
            const int sv0 = s_lds[e0], sv1 = s_lds[e1], sv2 = s_lds[e2], sv3 = s_lds[e3];
            const float a0 = a_lds[e0 * NH + h], a1 = a_lds[e1 * NH + h];
            const float a2 = a_lds[e2 * NH + h], a3 = a_lds[e3 * NH + h];
            const bf16x8 f0 = *(const bf16x8*)(ft + (size_t)sv0 * HD + il * 8);
            const bf16x8 f1 = *(const bf16x8*)(ft + (size_t)sv1 * HD + il * 8);
            const bf16x8 f2 = *(const bf16x8*)(ft + (size_t)sv2 * HD + il * 8);
            const bf16x8 f3 = *(const bf16x8*)(ft + (size_t)sv3 * HD + il * 8);
#pragma unroll
            for (int k = 0; k < 8; ++k) acc[k] = fmaf(a0, (float)f0[k], acc[k]);
#pragma unroll
            for (int k = 0; k < 8; ++k) acc[k] = fmaf(a1, (float)f1[k], acc[k]);
#pragma unroll
            for (int k = 0; k < 8; ++k) acc[k] = fmaf(a2, (float)f2[k], acc[k]);
#pragma unroll
            for (int k = 0; k < 8; ++k) acc[k] = fmaf(a3, (float)f3[k], acc[k]);
        }
        __syncthreads();
    }
#pragma unroll
    for (int s = 1; s < 64; s <<= 1) {
        ssum.x += __shfl_xor(ssum.x, s);
        ssum.y += __shfl_xor(ssum.y, s);
        ssum.z += __shfl_xor(ssum.z, s);
        ssum.w += __shfl_xor(ssum.w, s);
    }
#pragma unroll
    for (int k = 0; k < 8; ++k) {
        acc[k] += __shfl_xor(acc[k], 16);
        acc[k] += __shfl_xor(acc[k], 32);
    }
    const float sumh = (h == 0) ? ssum.x : (h == 1) ? ssum.y : (h == 2) ? ssum.z : ssum.w;
    const float inv = 1.f / sumh;
    if (q < 2) {
        const int b = q * 4;
        outp[il * 2 + q] = make_float4(acc[b] * inv, acc[b + 1] * inv,
                                       acc[b + 2] * inv, acc[b + 3] * inv);
    }
}

// ---------------------------------------------------------------------------
extern "C" void kernel_launch(void* const* d_in, const int* in_sizes, int n_in,
                              void* d_out, int out_size, void* d_ws, size_t ws_size,
                              hipStream_t stream) {
    const float* feat   = (const float*)d_in[0];
    const float* fc_w   = (const float*)d_in[1];
    const float* attn_l = (const float*)d_in[2];
    const float* attn_r = (const float*)d_in[3];
    const int*   src    = (const int*)d_in[4];
    const int*   dst    = (const int*)d_in[5];
    const int N = in_sizes[0] / IN_F;
    const int E = in_sizes[4];
    float* out = (float*)d_out;

    char* wp = (char*)d_ws;
    __bf16* ft = (__bf16*)wp;    wp += (size_t)N * HD * 2;  // 25.6 MB
    __bf16* wfrag = (__bf16*)wp; wp += 32768 * 2;           // 64 KB
    float* el  = (float*)wp; wp += (size_t)N * NH * 4;      // 1.6 MB
    float* er  = (float*)wp; wp += (size_t)N * NH * 4;      // 1.6 MB
    int* deg   = (int*)wp;   wp += (size_t)N * 4;
    int* off   = (int*)wp;   wp += (size_t)N * 4;
    int* bsum  = (int*)wp;   wp += 1024;
    int* boff  = (int*)wp;   wp += 1024;
    int* rank  = (int*)wp;   wp += (size_t)E * 4;
    int* ssrc  = (int*)wp;   wp += (size_t)E * 4;

    hipMemsetAsync(deg, 0, (size_t)N * 4, stream);

    wprep_k<<<dim3(16), dim3(256), 0, stream>>>(fc_w, wfrag);
    gemm_ft_fused<<<dim3((N + 127) / 128), dim3(256), 0, stream>>>(
        feat, wfrag, attn_l, attn_r, ft, el, er, N);
    deg_rank_k<<<dim3((E + 255) / 256), dim3(256), 0, stream>>>(dst, deg, rank, E);
    const int nblk = (N + 1023) >> 10;
    scan1_k<<<dim3(nblk), dim3(1024), 0, stream>>>(deg, off, bsum, N);
    scan2_k<<<dim3(1), dim3(128), 0, stream>>>(bsum, boff, nblk);
    scatter_k<<<dim3((E + 255) / 256), dim3(256), 0, stream>>>(src, dst, off, boff, rank, ssrc, E);
    aggregate_k<<<dim3(N), dim3(64), 0, stream>>>(ft, el, er, deg, off, boff, ssrc, out, N);
}